// Round 6
// baseline (401.439 us; speedup 1.0000x reference)
//
#include <hip/hip_runtime.h>
#include <hip/hip_bf16.h>

#define D 256
#define NC 512
#define NROWS 131072L

// out layout (fp32 elements), reference return order
#define OFF_ZQ   0L
#define OFF_VQ   33554432L
#define OFF_CM   33554433L
#define OFF_IDX  33554434L
#define OFF_HIST 33685506L

// ws float offsets
#define WS_LPART 0        // [0,2048)        per-block loss partials (written unconditionally)
#define WS_LOSSA 2048     // ambiguous-row loss (atomic)
#define WS_HIST  2112     // [2112,2624)
#define WS_E2    2624     // [2624,3136)
#define WS_CNT   3136     // ambig count (int)
#define WS_AMB   3200     // [3200,134272)   ambig row list (int)
#define WS_FIDX  134272   // [134272,265344) final idx (int)
#define WS_EF16  265344   // e as f16: 512*256 halves = 65536 floats -> [265344,330880)
#define WS_NEED  (330880L * 4)

#define MARGIN 0.125f

typedef __attribute__((ext_vector_type(8))) _Float16 f16x8;
typedef __attribute__((ext_vector_type(4))) float f32x4;

// prep: per-code ||e||^2, f16 conversion, and zero the small accumulators
__global__ void vq_prep(const float* __restrict__ e, float* __restrict__ ws) {
    int c = blockIdx.x, t = threadIdx.x;   // 512 blocks x 64 thr
    float4 v = *(const float4*)(e + c * D + t * 4);
    float s = v.x * v.x + v.y * v.y + v.z * v.z + v.w * v.w;
    #pragma unroll
    for (int off = 32; off; off >>= 1) s += __shfl_xor(s, off);
    if (t == 0) ws[WS_E2 + c] = s;
    union { _Float16 h[4]; ushort4 u; } p;
    p.h[0] = (_Float16)v.x; p.h[1] = (_Float16)v.y;
    p.h[2] = (_Float16)v.z; p.h[3] = (_Float16)v.w;
    unsigned short* ef16 = (unsigned short*)(ws + WS_EF16);
    *(ushort4*)&ef16[c * D + t * 4] = p.u;
    if (c == 0) {
        #pragma unroll
        for (int j = 0; j < 8; ++j) ws[WS_HIST + j * 64 + t] = 0.0f;
        if (t == 0) { ((int*)(ws + WS_CNT))[0] = 0; ws[WS_LOSSA] = 0.0f; }
    }
}

// 64x512 tile per block. 8 waves, wave w owns codes [w*64, w*64+64), all 64 rows.
// No barriers in the K-loop: B frags loaded global->VGPR (L2-resident), z in LDS.
// Fused epilogue writes z_q_st + loss partial for margin-certified rows.
__global__ __launch_bounds__(512, 4)
void vq_gemm(const float* __restrict__ z, const float* __restrict__ e,
             const _Float16* __restrict__ ef16, const float* __restrict__ e2,
             int* __restrict__ fidx, int* __restrict__ acnt, int* __restrict__ alist,
             float* __restrict__ out, float* __restrict__ lpart) {
    __shared__ __align__(16) unsigned short zh[64 * 264];   // 33 KB, pad->2-way free
    __shared__ float red[64 * 8 * 3];                       // 6 KB
    __shared__ int idx_s[64];
    __shared__ int amb_s[64];
    __shared__ float rs[8];

    const int tid = threadIdx.x;
    const int w = tid >> 6, l = tid & 63, q = l >> 4, ln = l & 15;
    const long row0 = (long)blockIdx.x * 64;
    const float* zb = z + row0 * D;

    // ---- stage z once: fp32 -> f16 (RNE), padded LDS ----
    #pragma unroll
    for (int j = 0; j < 8; ++j) {
        int c = j * 512 + tid;              // float4 chunk 0..4095
        int row = c >> 6, c4 = (c & 63) * 4;
        float4 av = *(const float4*)(zb + row * D + c4);
        union { _Float16 h[4]; ushort4 u; } p;
        p.h[0] = (_Float16)av.x; p.h[1] = (_Float16)av.y;
        p.h[2] = (_Float16)av.z; p.h[3] = (_Float16)av.w;
        *(ushort4*)&zh[row * 264 + c4] = p.u;
    }
    __syncthreads();                        // the ONLY barrier before the merge

    f32x4 acc[4][4];
    #pragma unroll
    for (int mt = 0; mt < 4; ++mt)
        #pragma unroll
        for (int nt = 0; nt < 4; ++nt) acc[mt][nt] = (f32x4){0.f, 0.f, 0.f, 0.f};

    const _Float16* ebase = ef16 + (w * 64 + ln) * D + q * 8;   // lane's code row
    const _Float16* zh16 = (const _Float16*)zh;

    for (int s = 0; s < 8; ++s) {
        f16x8 bfr[4], af[4];
        #pragma unroll
        for (int nt = 0; nt < 4; ++nt)      // global 16B, L2-hot, async
            bfr[nt] = *(const f16x8*)(ebase + nt * 16 * D + s * 32);
        #pragma unroll
        for (int mt = 0; mt < 4; ++mt)      // ds_read_b128, 2-way (free)
            af[mt] = *(const f16x8*)&zh16[(mt * 16 + ln) * 264 + s * 32 + q * 8];
        #pragma unroll
        for (int mt = 0; mt < 4; ++mt)
            #pragma unroll
            for (int nt = 0; nt < 4; ++nt)
                acc[mt][nt] = __builtin_amdgcn_mfma_f32_16x16x32_f16(af[mt], bfr[nt], acc[mt][nt], 0, 0, 0);
    }

    // ---- per-row top-2 of sim = e2[col] - 2*dot over wave's 64 cols ----
    float e2v[4];
    #pragma unroll
    for (int nt = 0; nt < 4; ++nt) e2v[nt] = e2[w * 64 + nt * 16 + ln];

    #pragma unroll
    for (int mt = 0; mt < 4; ++mt) {
        #pragma unroll
        for (int r = 0; r < 4; ++r) {
            float v1 = -3.0e38f, v2 = -3.0e38f; int i1 = 0;
            #pragma unroll
            for (int nt = 0; nt < 4; ++nt) {   // ascending code order
                float v = e2v[nt] - 2.0f * acc[mt][nt][r];
                int c = w * 64 + nt * 16 + ln;
                if (v > v1) { v2 = v1; v1 = v; i1 = c; }
                else if (v > v2) v2 = v;
            }
            #pragma unroll
            for (int off = 1; off < 16; off <<= 1) {   // 16-lane group butterfly
                float ov1 = __shfl_xor(v1, off);
                float ov2 = __shfl_xor(v2, off);
                int   oi1 = __shfl_xor(i1, off);
                if (ov1 > v1 || (ov1 == v1 && oi1 < i1)) {
                    v2 = fmaxf(v1, ov2); v1 = ov1; i1 = oi1;
                } else {
                    v2 = fmaxf(v2, ov1);
                }
            }
            if (ln == 0) {
                int rr = mt * 16 + q * 4 + r;          // C/D row mapping
                red[rr * 24 + w * 3 + 0] = v1;
                red[rr * 24 + w * 3 + 1] = (float)i1;
                red[rr * 24 + w * 3 + 2] = v2;
            }
        }
    }
    __syncthreads();
    // ---- 8-way code-group merge (ascending order keeps lower-index ties) ----
    if (tid < 64) {
        float v1 = -3.0e38f, v2 = -3.0e38f; int i1 = 0;
        #pragma unroll
        for (int g = 0; g < 8; ++g) {
            float rv1 = red[tid * 24 + g * 3 + 0];
            int   ri  = (int)red[tid * 24 + g * 3 + 1];
            float rv2 = red[tid * 24 + g * 3 + 2];
            if (rv1 > v1) { v2 = fmaxf(v1, rv2); v1 = rv1; i1 = ri; }
            else v2 = fmaxf(v2, rv1);
        }
        idx_s[tid] = i1;
        int amb = (v1 - v2 < MARGIN) ? 1 : 0;
        amb_s[tid] = amb;
        fidx[row0 + tid] = i1;
        if (amb) {
            int p = atomicAdd(acnt, 1);
            alist[p] = (int)(row0 + tid);
        }
    }
    __syncthreads();

    // ---- fused epilogue for certain rows: z_q_st + loss (z L3-hot, e L2-hot) ----
    float ls = 0.f;
    #pragma unroll
    for (int j = 0; j < 8; ++j) {
        int c = j * 512 + tid;
        int rl = c >> 6, c4 = (c & 63) * 4;
        if (!amb_s[rl]) {
            int idx = idx_s[rl];
            float4 zv = *(const float4*)(zb + rl * D + c4);
            float4 ev = *(const float4*)(e + idx * D + c4);
            float4 dq;
            dq.x = ev.x - zv.x; dq.y = ev.y - zv.y; dq.z = ev.z - zv.z; dq.w = ev.w - zv.w;
            float4 o;
            o.x = zv.x + dq.x; o.y = zv.y + dq.y; o.z = zv.z + dq.z; o.w = zv.w + dq.w;
            *(float4*)(out + OFF_ZQ + (row0 + rl) * D + c4) = o;
            ls += dq.x * dq.x + dq.y * dq.y + dq.z * dq.z + dq.w * dq.w;
        }
    }
    #pragma unroll
    for (int off = 32; off; off >>= 1) ls += __shfl_xor(ls, off);
    if (l == 0) rs[w] = ls;
    __syncthreads();
    if (tid == 0) {
        float t = 0.f;
        #pragma unroll
        for (int i = 0; i < 8; ++i) t += rs[i];
        lpart[blockIdx.x] = t;
    }
}

// exact fp32 re-argmax for ambiguous rows (32-row groups share the e-stream),
// finishes z_q_st + loss + fidx for those rows.
__global__ __launch_bounds__(256, 2)
void vq_refine(const float* __restrict__ z, const float* __restrict__ e,
               const float* __restrict__ e2, const int* __restrict__ acnt,
               const int* __restrict__ alist, int* __restrict__ fidx,
               float* __restrict__ out, float* __restrict__ loss_amb) {
    __shared__ __align__(16) float z_s[32][D];        // 32 KB
    __shared__ __align__(16) float e_s[16][NC + 4];   // 33 KB
    __shared__ int rowg[32];
    __shared__ int idx_s[32];
    const int tid = threadIdx.x, lane = tid & 63, w = tid >> 6;
    const int cnt = *acnt;
    float lacc = 0.f;
    for (int g = blockIdx.x; g * 32 < cnt; g += gridDim.x) {
        const int base = g * 32;
        __syncthreads();   // prev iteration done with z_s/rowg/idx_s
        if (tid < 32) rowg[tid] = alist[min(base + tid, cnt - 1)];  // pad w/ last
        __syncthreads();
        #pragma unroll
        for (int j = 0; j < 8; ++j) {      // gather 32 z rows
            int c = j * 256 + tid, rl = c >> 6, c4 = (c & 63) * 4;
            *(float4*)&z_s[rl][c4] = *(const float4*)(z + (long)rowg[rl] * D + c4);
        }
        float acc[8][8];
        #pragma unroll
        for (int r = 0; r < 8; ++r)
            #pragma unroll
            for (int c = 0; c < 8; ++c) acc[r][c] = 0.0f;
        const int r0 = w * 8, c_lo = lane * 4;
        for (int kc = 0; kc < D; kc += 16) {
            __syncthreads();
            #pragma unroll
            for (int p = 0; p < 8; ++p) {
                int c = p * 64 + (tid >> 2), kk4 = (tid & 3) * 4;
                float4 v = *(const float4*)(e + c * D + kc + kk4);
                e_s[kk4 + 0][c] = v.x; e_s[kk4 + 1][c] = v.y;
                e_s[kk4 + 2][c] = v.z; e_s[kk4 + 3][c] = v.w;
            }
            __syncthreads();
            #pragma unroll
            for (int k4 = 0; k4 < 16; k4 += 4) {
                float zr[8][4];
                #pragma unroll
                for (int r = 0; r < 8; ++r) *(float4*)zr[r] = *(const float4*)&z_s[r0 + r][kc + k4];
                #pragma unroll
                for (int kk = 0; kk < 4; ++kk) {
                    float ev[8];
                    *(float4*)&ev[0] = *(const float4*)&e_s[k4 + kk][c_lo];
                    *(float4*)&ev[4] = *(const float4*)&e_s[k4 + kk][c_lo + 256];
                    #pragma unroll
                    for (int r = 0; r < 8; ++r)
                        #pragma unroll
                        for (int c = 0; c < 8; ++c) acc[r][c] = fmaf(zr[r][kk], ev[c], acc[r][c]);
                }
            }
        }
        float e2v[8];
        #pragma unroll
        for (int gg = 0; gg < 2; ++gg)
            #pragma unroll
            for (int i = 0; i < 4; ++i) e2v[gg * 4 + i] = e2[gg * 256 + c_lo + i];
        #pragma unroll
        for (int r = 0; r < 8; ++r) {
            float bvv = -3.0e38f; int bc = 0;
            #pragma unroll
            for (int c = 0; c < 8; ++c) {
                int col = (c >> 2) * 256 + c_lo + (c & 3);
                float v = e2v[c] - 2.0f * acc[r][c];
                if (v > bvv) { bvv = v; bc = col; }
            }
            #pragma unroll
            for (int off = 32; off; off >>= 1) {
                float ov = __shfl_xor(bvv, off); int oc = __shfl_xor(bc, off);
                if (ov > bvv || (ov == bvv && oc < bc)) { bvv = ov; bc = oc; }
            }
            if (lane == 0) idx_s[r0 + r] = bc;
        }
        __syncthreads();
        if (tid < 32 && base + tid < cnt) fidx[rowg[tid]] = idx_s[tid];
        // finish these rows: z_q_st + loss (z in LDS fp32, e L2-hot)
        #pragma unroll
        for (int j = 0; j < 8; ++j) {
            int c = j * 256 + tid, rl = c >> 6, c4 = (c & 63) * 4;
            if (base + rl < cnt) {
                int idx = idx_s[rl];
                float4 zv = *(const float4*)&z_s[rl][c4];
                float4 ev = *(const float4*)(e + idx * D + c4);
                float4 dq;
                dq.x = ev.x - zv.x; dq.y = ev.y - zv.y; dq.z = ev.z - zv.z; dq.w = ev.w - zv.w;
                float4 o;
                o.x = zv.x + dq.x; o.y = zv.y + dq.y; o.z = zv.z + dq.z; o.w = zv.w + dq.w;
                *(float4*)(out + OFF_ZQ + (long)rowg[rl] * D + c4) = o;
                lacc += dq.x * dq.x + dq.y * dq.y + dq.z * dq.z + dq.w * dq.w;
            }
        }
    }
    #pragma unroll
    for (int off = 32; off; off >>= 1) lacc += __shfl_xor(lacc, off);
    __shared__ float rsum[4];
    if (lane == 0) rsum[w] = lacc;
    __syncthreads();
    if (tid == 0) {
        float t = rsum[0] + rsum[1] + rsum[2] + rsum[3];
        if (t != 0.f) atomicAdd(loss_amb, t);
    }
}

// idx output + histogram via LDS (64 blocks -> <=64 serialized atomics per bin)
__global__ __launch_bounds__(256)
void vq_hist(const int* __restrict__ fidx, float* __restrict__ out,
             float* __restrict__ hist) {
    __shared__ int h[NC];
    const int t = threadIdx.x;
    h[t] = 0; h[t + 256] = 0;
    __syncthreads();
    const long base = (long)blockIdx.x * 2048;
    #pragma unroll
    for (int j = 0; j < 8; ++j) {
        long i = base + j * 256 + t;
        int idx = fidx[i];
        out[OFF_IDX + i] = (float)idx;
        atomicAdd(&h[idx], 1);
    }
    __syncthreads();
    #pragma unroll
    for (int j = 0; j < 2; ++j) {
        int k = j * 256 + t;
        int c = h[k];
        if (c) atomicAdd(&hist[k], (float)c);
    }
}

__global__ void vq_fin(const float* __restrict__ ws, float* __restrict__ out) {
    __shared__ float sred[16];
    const int t = threadIdx.x, lane = t & 63, w = t >> 6;  // 1024 threads
    float s = ws[WS_LPART + t] + ws[WS_LPART + t + 1024];
    #pragma unroll
    for (int off = 32; off; off >>= 1) s += __shfl_xor(s, off);
    if (lane == 0) sred[w] = s;
    __syncthreads();
    if (t == 0) {
        float tot = ws[WS_LOSSA];
        #pragma unroll
        for (int i = 0; i < 16; ++i) tot += sred[i];
        float m = tot / 33554432.0f;     // mean((z_q - z)^2)
        out[OFF_VQ] = m;
        out[OFF_CM] = 0.25f * m;
    }
    if (t < NC) out[OFF_HIST + t] = ws[WS_HIST + t];
}

// ================= fallback (ws too small): round-2 fp32 path =================
__global__ __launch_bounds__(256, 2)
void vq_main_fb(const float* __restrict__ z, const float* __restrict__ e,
                const float* __restrict__ e2, float* __restrict__ out,
                float* __restrict__ ws_loss, float* __restrict__ ws_hist) {
    __shared__ __align__(16) float z_s[32][D];
    __shared__ __align__(16) float e_s[16][NC + 4];
    __shared__ int   idx_s[32];
    __shared__ float red_s[4];
    const int tid = threadIdx.x, lane = tid & 63, w = tid >> 6;
    const long row0 = (long)blockIdx.x * 32;
    {
        const float4* zg = (const float4*)(z + row0 * D);
        float4* zs = (float4*)(&z_s[0][0]);
        #pragma unroll
        for (int i = 0; i < 8; ++i) zs[i * 256 + tid] = zg[i * 256 + tid];
    }
    float acc[8][8];
    #pragma unroll
    for (int r = 0; r < 8; ++r)
        #pragma unroll
        for (int c = 0; c < 8; ++c) acc[r][c] = 0.0f;
    const int r0 = w * 8, c_lo = lane * 4;
    for (int kc = 0; kc < D; kc += 16) {
        __syncthreads();
        #pragma unroll
        for (int p = 0; p < 8; ++p) {
            int c = p * 64 + (tid >> 2), kk4 = (tid & 3) * 4;
            float4 v = *(const float4*)(e + c * D + kc + kk4);
            e_s[kk4 + 0][c] = v.x; e_s[kk4 + 1][c] = v.y;
            e_s[kk4 + 2][c] = v.z; e_s[kk4 + 3][c] = v.w;
        }
        __syncthreads();
        #pragma unroll
        for (int k4 = 0; k4 < 16; k4 += 4) {
            float zr[8][4];
            #pragma unroll
            for (int r = 0; r < 8; ++r) *(float4*)zr[r] = *(const float4*)&z_s[r0 + r][kc + k4];
            #pragma unroll
            for (int kk = 0; kk < 4; ++kk) {
                float ev[8];
                *(float4*)&ev[0] = *(const float4*)&e_s[k4 + kk][c_lo];
                *(float4*)&ev[4] = *(const float4*)&e_s[k4 + kk][c_lo + 256];
                #pragma unroll
                for (int r = 0; r < 8; ++r)
                    #pragma unroll
                    for (int c = 0; c < 8; ++c) acc[r][c] = fmaf(zr[r][kk], ev[c], acc[r][c]);
            }
        }
    }
    float e2v[8];
    #pragma unroll
    for (int g = 0; g < 2; ++g)
        #pragma unroll
        for (int i = 0; i < 4; ++i) e2v[g * 4 + i] = e2[g * 256 + c_lo + i];
    #pragma unroll
    for (int r = 0; r < 8; ++r) {
        float bvv = -3.0e38f; int bc = 0;
        #pragma unroll
        for (int c = 0; c < 8; ++c) {
            int col = (c >> 2) * 256 + c_lo + (c & 3);
            float v = e2v[c] - 2.0f * acc[r][c];
            if (v > bvv) { bvv = v; bc = col; }
        }
        #pragma unroll
        for (int off = 32; off; off >>= 1) {
            float ov = __shfl_xor(bvv, off); int oc = __shfl_xor(bc, off);
            if (ov > bvv || (ov == bvv && oc < bc)) { bvv = ov; bc = oc; }
        }
        if (lane == 0) idx_s[r0 + r] = bc;
    }
    __syncthreads();
    if (tid < 32) {
        int bc = idx_s[tid];
        out[OFF_IDX + row0 + tid] = (float)bc;
        atomicAdd(&ws_hist[bc], 1.0f);
    }
    float lsum = 0.0f;
    for (int r = 0; r < 32; ++r) {
        int idx = idx_s[r];
        float ev = e[idx * D + tid];
        float zv = z_s[r][tid];
        float dq = ev - zv;
        out[OFF_ZQ + (row0 + r) * D + tid] = zv + dq;
        lsum += dq * dq;
    }
    #pragma unroll
    for (int off = 32; off; off >>= 1) lsum += __shfl_xor(lsum, off);
    if (lane == 0) red_s[w] = lsum;
    __syncthreads();
    if (tid == 0) atomicAdd(ws_loss, red_s[0] + red_s[1] + red_s[2] + red_s[3]);
}

__global__ void vq_init_fb(float* __restrict__ ws) {
    int t = threadIdx.x;
    if (t < 513) ws[t] = 0.0f;
}
__global__ void vq_e2_fb(const float* __restrict__ e, float* __restrict__ e2) {
    int c = blockIdx.x, l = threadIdx.x;
    float4 v = *(const float4*)(e + c * D + l * 4);
    float s = v.x * v.x + v.y * v.y + v.z * v.z + v.w * v.w;
    #pragma unroll
    for (int off = 32; off; off >>= 1) s += __shfl_xor(s, off);
    if (l == 0) e2[c] = s;
}
__global__ void vq_fin_fb(const float* __restrict__ ws, float* __restrict__ out) {
    int t = blockIdx.x * blockDim.x + threadIdx.x;
    if (t < NC) out[OFF_HIST + t] = ws[1 + t];
    if (t == NC) {
        float m = ws[0] / 33554432.0f;
        out[OFF_VQ] = m; out[OFF_CM] = 0.25f * m;
    }
}

extern "C" void kernel_launch(void* const* d_in, const int* in_sizes, int n_in,
                              void* d_out, int out_size, void* d_ws, size_t ws_size,
                              hipStream_t stream) {
    const float* z = (const float*)d_in[0];
    const float* e = (const float*)d_in[1];
    float* out = (float*)d_out;
    float* ws  = (float*)d_ws;

    if (ws_size >= (size_t)WS_NEED) {
        float* lpart = ws + WS_LPART;
        float* lossa = ws + WS_LOSSA;
        float* hist  = ws + WS_HIST;
        float* e2    = ws + WS_E2;
        int*   acnt  = (int*)(ws + WS_CNT);
        int*   alist = (int*)(ws + WS_AMB);
        int*   fidx  = (int*)(ws + WS_FIDX);
        const _Float16* ef16 = (const _Float16*)(ws + WS_EF16);

        vq_prep<<<NC, 64, 0, stream>>>(e, ws);
        vq_gemm<<<2048, 512, 0, stream>>>(z, e, ef16, e2, fidx, acnt, alist, out, lpart);
        vq_refine<<<512, 256, 0, stream>>>(z, e, e2, acnt, alist, fidx, out, lossa);
        vq_hist<<<64, 256, 0, stream>>>(fidx, out, hist);
        vq_fin<<<1, 1024, 0, stream>>>(ws, out);
    } else {
        float* ws_loss = ws;
        float* ws_hist = ws + 1;
        float* ws_e2   = ws + 513;
        vq_init_fb<<<1, 1024, 0, stream>>>(ws);
        vq_e2_fb<<<NC, 64, 0, stream>>>(e, ws_e2);
        vq_main_fb<<<4096, 256, 0, stream>>>(z, e, ws_e2, out, ws_loss, ws_hist);
        vq_fin_fb<<<3, 256, 0, stream>>>(ws, out);
    }
}